// Round 1
// baseline (31411.676 us; speedup 1.0000x reference)
//
#include <hip/hip_runtime.h>
#include <math.h>

// Problem constants
#define DIMSZ 1024
#define DEPTH 6
#define HEADS 16
#define DHEAD 64
#define BATCH 2
#define SEQ   1024
#define DFF   2730          // int(1024*4*2/3)
#define NTOK  (BATCH*SEQ)   // 2048

// ---------------- block reductions (256 threads) ----------------
__device__ __forceinline__ float block_reduce_sum256(float v, float* red) {
    int tid = threadIdx.x;
    red[tid] = v; __syncthreads();
    #pragma unroll
    for (int s = 128; s > 0; s >>= 1) {
        if (tid < s) red[tid] += red[tid + s];
        __syncthreads();
    }
    float r = red[0]; __syncthreads();
    return r;
}
__device__ __forceinline__ float block_reduce_max256(float v, float* red) {
    int tid = threadIdx.x;
    red[tid] = v; __syncthreads();
    #pragma unroll
    for (int s = 128; s > 0; s >>= 1) {
        if (tid < s) red[tid] = fmaxf(red[tid], red[tid + s]);
        __syncthreads();
    }
    float r = red[0]; __syncthreads();
    return r;
}

// ---------------- generic fp32 GEMM, 128x128 tile, 8x8 micro ----------------
// C(MxN) = A(MxK) @ W(KxN); modes:
//   0: C = acc (+bias)        1: C += acc        2: C += (acc (+bias)) * adaz[b,n]
// adaz is (BATCH, N) with b = row >> 10 (1024 tokens per batch).
__global__ __launch_bounds__(256)
void gemm_f32(const float* __restrict__ A, const float* __restrict__ W,
              const float* __restrict__ bias, const float* __restrict__ adaz,
              float* __restrict__ C, int M, int N, int K, int mode)
{
    __shared__ float As[16][132];   // padded: conflict-free stores, aligned b128 reads
    __shared__ float Bs[16][128];
    const int tid = threadIdx.x;
    const int tx = tid & 15, ty = tid >> 4;
    const int m0 = blockIdx.y * 128, n0 = blockIdx.x * 128;

    float acc[8][8];
    #pragma unroll
    for (int i = 0; i < 8; i++)
        #pragma unroll
        for (int j = 0; j < 8; j++) acc[i][j] = 0.f;

    for (int k0 = 0; k0 < K; k0 += 16) {
        #pragma unroll
        for (int i = 0; i < 8; i++) {
            int e = tid + i * 256;
            int m = e >> 4, k = e & 15;
            int gm = m0 + m, gk = k0 + k;
            float v = 0.f;
            if (gm < M && gk < K) v = A[(size_t)gm * K + gk];
            As[k][m] = v;
        }
        #pragma unroll
        for (int i = 0; i < 8; i++) {
            int e = tid + i * 256;
            int k = e >> 7, n = e & 127;
            int gk = k0 + k, gn = n0 + n;
            float v = 0.f;
            if (gk < K && gn < N) v = W[(size_t)gk * N + gn];
            Bs[k][n] = v;
        }
        __syncthreads();
        #pragma unroll
        for (int kk = 0; kk < 16; kk++) {
            float a[8], b[8];
            #pragma unroll
            for (int i = 0; i < 8; i++) a[i] = As[kk][ty * 8 + i];
            #pragma unroll
            for (int j = 0; j < 4; j++) b[j] = Bs[kk][tx * 4 + j];
            #pragma unroll
            for (int j = 0; j < 4; j++) b[4 + j] = Bs[kk][64 + tx * 4 + j];
            #pragma unroll
            for (int i = 0; i < 8; i++)
                #pragma unroll
                for (int j = 0; j < 8; j++) acc[i][j] = fmaf(a[i], b[j], acc[i][j]);
        }
        __syncthreads();
    }

    #pragma unroll
    for (int i = 0; i < 8; i++) {
        int gm = m0 + ty * 8 + i;
        if (gm >= M) continue;
        int bidx = gm >> 10;  // 1024 tokens per batch
        #pragma unroll
        for (int j = 0; j < 8; j++) {
            int gn = n0 + ((j < 4) ? (tx * 4 + j) : (64 + tx * 4 + (j - 4)));
            if (gn >= N) continue;
            float v = acc[i][j];
            if (bias) v += bias[gn];
            size_t idx = (size_t)gm * N + gn;
            if (mode == 0)      C[idx] = v;
            else if (mode == 1) C[idx] += v;
            else                C[idx] += v * adaz[(size_t)bidx * N + gn];
        }
    }
}

// ---------------- conditioning pipeline ----------------
__global__ void fourier_kernel(const float* __restrict__ times,
                               const float* __restrict__ fw,
                               float* __restrict__ fourier) {
    int b = blockIdx.x;
    int j = threadIdx.x;  // 512
    float t = times[b];
    float f = t * fw[j] * 6.2831853071795864f;
    fourier[b * 1025 + 1 + j]   = sinf(f);
    fourier[b * 1025 + 513 + j] = cosf(f);
    if (j == 0) fourier[b * 1025] = t;
}

// cond[b, col] = silu(fourier[b] @ tcond_w[:, col] + tcond_b[col]); col < 4096
__global__ __launch_bounds__(256)
void cond_kernel(const float* __restrict__ fourier, const float* __restrict__ Wt,
                 const float* __restrict__ bt, float* __restrict__ cond) {
    int col = blockIdx.x * 256 + threadIdx.x;
    float a0 = 0.f, a1 = 0.f;
    for (int r = 0; r < 1025; r++) {
        float w = Wt[(size_t)r * 4096 + col];
        a0 = fmaf(fourier[r], w, a0);
        a1 = fmaf(fourier[1025 + r], w, a1);
    }
    float bb = bt[col];
    a0 += bb; a1 += bb;
    cond[col]        = a0 / (1.f + expf(-a0));
    cond[4096 + col] = a1 / (1.f + expf(-a1));
}

// out[(l*BATCH+b)*Mcols+col] = (cond[b] @ W[l][:,col] + bias[l,col]) (opt sigmoid)
__global__ __launch_bounds__(256)
void film_gemv(const float* __restrict__ cond, const float* __restrict__ W,
               const float* __restrict__ bias, float* __restrict__ out,
               int Mcols, int sig) {
    int l = blockIdx.y;
    int col = blockIdx.x * 256 + threadIdx.x;
    const float* Wl = W + (size_t)l * 4096 * Mcols;
    float a0 = 0.f, a1 = 0.f;
    for (int r = 0; r < 4096; r++) {
        float w = Wl[(size_t)r * Mcols + col];
        a0 = fmaf(cond[r], w, a0);
        a1 = fmaf(cond[4096 + r], w, a1);
    }
    float bb = bias[(size_t)l * Mcols + col];
    a0 += bb; a1 += bb;
    if (sig) { a0 = 1.f / (1.f + expf(-a0)); a1 = 1.f / (1.f + expf(-a1)); }
    out[((size_t)l * BATCH + 0) * Mcols + col] = a0;
    out[((size_t)l * BATCH + 1) * Mcols + col] = a1;
}

// ---------------- LayerNorm + film ----------------
// film slice: (BATCH, 2048): [b, c] = g, [b, 1024+c] = beta
__global__ __launch_bounds__(256)
void ln_film_kernel(const float* __restrict__ x, const float* __restrict__ film,
                    float* __restrict__ xc) {
    __shared__ float red[256];
    int row = blockIdx.x;
    int b = row >> 10;
    int tid = threadIdx.x;
    float v[4];
    float s = 0.f, sq = 0.f;
    #pragma unroll
    for (int k = 0; k < 4; k++) {
        v[k] = x[(size_t)row * DIMSZ + tid + k * 256];
        s += v[k]; sq += v[k] * v[k];
    }
    s  = block_reduce_sum256(s, red);
    sq = block_reduce_sum256(sq, red);
    float mu = s * (1.f / 1024.f);
    float var = sq * (1.f / 1024.f) - mu * mu;
    float rstd = rsqrtf(var + 1e-5f);
    #pragma unroll
    for (int k = 0; k < 4; k++) {
        int c = tid + k * 256;
        float g  = film[(size_t)b * 2048 + c];
        float bb = film[(size_t)b * 2048 + 1024 + c];
        xc[(size_t)row * DIMSZ + c] = (v[k] - mu) * rstd * (g + 1.f) + bb;
    }
}

// ---------------- gates: sigmoid(xc @ gates_w) -> (NTOK, 16) ----------------
__global__ __launch_bounds__(256)
void gates_kernel(const float* __restrict__ xc, const float* __restrict__ W,
                  float* __restrict__ gates) {
    __shared__ float red[256];
    int row = blockIdx.x;
    int tid = threadIdx.x;
    int col = tid & 15, part = tid >> 4;  // 16 parts x 16 cols
    float acc = 0.f;
    int r0 = part * 64;
    for (int r = 0; r < 64; r++)
        acc = fmaf(xc[(size_t)row * DIMSZ + r0 + r], W[(r0 + r) * 16 + col], acc);
    red[tid] = acc; __syncthreads();
    #pragma unroll
    for (int s = 8; s > 0; s >>= 1) {
        if (part < s) red[part * 16 + col] += red[(part + s) * 16 + col];
        __syncthreads();
    }
    if (tid < 16) gates[(size_t)row * 16 + tid] = 1.f / (1.f + expf(-red[tid]));
}

// ---------------- RoPE in-place on q,k of qkv (B,N,3,H,64) ----------------
__global__ __launch_bounds__(256)
void rope_kernel(float* __restrict__ qkv, const float* __restrict__ freqs) {
    int idx = blockIdx.x * 256 + threadIdx.x;  // (((bn)*2 + t)*16 + h)*32 + p
    int p = idx & 31;
    int h = (idx >> 5) & 15;
    int t = (idx >> 9) & 1;
    int bn = idx >> 10;
    int n = bn & 1023;
    size_t base = ((size_t)bn * 3 + t) * 1024 + h * 64 + 2 * p;
    float f = freqs[n * 64 + 2 * p];  // repeated pairs: [n,2p]==[n,2p+1]
    float c = cosf(f), sn = sinf(f);
    float x0 = qkv[base], x1 = qkv[base + 1];
    qkv[base]     = x0 * c - x1 * sn;
    qkv[base + 1] = x1 * c + x0 * sn;
}

// vr (B,N,H*64) = v slice of qkv (pre-mix, post-GEMM; rope doesn't touch v)
__global__ __launch_bounds__(256)
void copy_vr_kernel(const float* __restrict__ qkv, float* __restrict__ vr) {
    int idx = blockIdx.x * 256 + threadIdx.x;  // < NTOK*1024
    int bn = idx >> 10, c = idx & 1023;
    vr[idx] = qkv[((size_t)bn * 3 + 2) * 1024 + c];
}

// ---------------- attention: one block per (b,h,i) ----------------
// scores -> softcap -> causal softmax -> o = P@V (v mixed w/ vr for layers>0),
// gate applied, output (B,N,H*64)
__global__ __launch_bounds__(256)
void attn_kernel(const float* __restrict__ qkv, const float* __restrict__ vr,
                 const float* __restrict__ gates, float* __restrict__ o,
                 int mix) {
    __shared__ float sc[1024];
    __shared__ float qs[64];
    __shared__ float red[256];
    __shared__ float red2[256];
    int blk = blockIdx.x;          // ((b*H + h)*N + i)
    int i = blk & 1023;
    int h = (blk >> 10) & 15;
    int b = blk >> 14;
    int tid = threadIdx.x;
    size_t bn_i = (size_t)b * 1024 + i;

    if (tid < 64) qs[tid] = qkv[(bn_i * 3 + 0) * 1024 + h * 64 + tid];
    __syncthreads();

    float lmax = -3.4e38f;
    for (int j = tid; j <= i; j += 256) {
        const float4* kr4 = (const float4*)(qkv + (((size_t)b * 1024 + j) * 3 + 1) * 1024 + h * 64);
        float s = 0.f;
        #pragma unroll
        for (int d4 = 0; d4 < 16; d4++) {
            float4 kk = kr4[d4];
            s = fmaf(qs[4 * d4 + 0], kk.x, s);
            s = fmaf(qs[4 * d4 + 1], kk.y, s);
            s = fmaf(qs[4 * d4 + 2], kk.z, s);
            s = fmaf(qs[4 * d4 + 3], kk.w, s);
        }
        s *= 0.125f;                    // DIM_HEAD^-0.5
        s = 50.f * tanhf(s * 0.02f);    // softcap
        sc[j] = s;
        lmax = fmaxf(lmax, s);
    }
    float m = block_reduce_max256(lmax, red);

    float lsum = 0.f;
    for (int j = tid; j <= i; j += 256) {
        float e = expf(sc[j] - m);
        sc[j] = e;
        lsum += e;
    }
    float l = block_reduce_sum256(lsum, red);

    int part = tid >> 6, d = tid & 63;
    float acc = 0.f;
    for (int j = part; j <= i; j += 4) {
        size_t bn_j = (size_t)b * 1024 + j;
        float vv = qkv[(bn_j * 3 + 2) * 1024 + h * 64 + d];
        if (mix) vv = 0.5f * (vv + vr[bn_j * 1024 + h * 64 + d]);
        acc = fmaf(sc[j], vv, acc);
    }
    red2[tid] = acc;
    __syncthreads();
    if (tid < 64) {
        float sum = red2[tid] + red2[64 + tid] + red2[128 + tid] + red2[192 + tid];
        float gate = gates[bn_i * 16 + h];
        o[(bn_i) * 1024 + h * 64 + tid] = sum / l * gate;
    }
}

// ---------------- GEGLU: act = gelu_exact(h[:,DFF+c]) * h[:,c] ----------------
__global__ __launch_bounds__(256)
void geglu_kernel(const float* __restrict__ h, float* __restrict__ act) {
    int c = blockIdx.x * 256 + threadIdx.x;
    int row = blockIdx.y;
    if (c >= DFF) return;
    float a = h[(size_t)row * (2 * DFF) + c];
    float g = h[(size_t)row * (2 * DFF) + DFF + c];
    float gl = 0.5f * g * (1.f + erff(g * 0.70710678118654752f));
    act[(size_t)row * DFF + c] = gl * a;
}

// ---------------- final: unit-norm * 32 * (gamma+1) ----------------
__global__ __launch_bounds__(256)
void final_kernel(const float* __restrict__ x, const float* __restrict__ gamma,
                  float* __restrict__ out) {
    __shared__ float red[256];
    int row = blockIdx.x;
    int tid = threadIdx.x;
    float v[4]; float sq = 0.f;
    #pragma unroll
    for (int k = 0; k < 4; k++) {
        v[k] = x[(size_t)row * DIMSZ + tid + k * 256];
        sq += v[k] * v[k];
    }
    sq = block_reduce_sum256(sq, red);
    float norm = sqrtf(sq);
    float rs = 32.f / fmaxf(norm, 1e-12f);
    #pragma unroll
    for (int k = 0; k < 4; k++) {
        int c = tid + k * 256;
        out[(size_t)row * DIMSZ + c] = v[k] * rs * (gamma[c] + 1.f);
    }
}

extern "C" void kernel_launch(void* const* d_in, const int* in_sizes, int n_in,
                              void* d_out, int out_size, void* d_ws, size_t ws_size,
                              hipStream_t stream) {
    const float* in_x    = (const float*)d_in[0];
    const float* times   = (const float*)d_in[1];
    const float* rfreqs  = (const float*)d_in[2];
    const float* fw      = (const float*)d_in[3];
    const float* tcond_w = (const float*)d_in[4];
    const float* tcond_b = (const float*)d_in[5];
    const float* skip_w  = (const float*)d_in[6];
    const float* afilm_w = (const float*)d_in[7];
    const float* afilm_b = (const float*)d_in[8];
    const float* aadaz_w = (const float*)d_in[9];
    const float* aadaz_b = (const float*)d_in[10];
    const float* qkv_w   = (const float*)d_in[11];
    const float* gates_w = (const float*)d_in[12];
    const float* out_w   = (const float*)d_in[13];
    const float* ffilm_w = (const float*)d_in[14];
    const float* ffilm_b = (const float*)d_in[15];
    const float* fadaz_w = (const float*)d_in[16];
    const float* fadaz_b = (const float*)d_in[17];
    const float* ff_w1   = (const float*)d_in[18];
    const float* ff_b1   = (const float*)d_in[19];
    const float* ff_w2   = (const float*)d_in[20];
    const float* ff_b2   = (const float*)d_in[21];
    const float* gamma   = (const float*)d_in[22];
    float* out = (float*)d_out;

    // workspace layout (~151 MB total)
    float* ws = (float*)d_ws;
    size_t off = 0;
    auto alloc = [&](size_t n) { float* p = ws + off; off += n; return p; };
    float* fourier   = alloc(BATCH * 1025);
    float* cond      = alloc(BATCH * 4096);
    float* film_attn = alloc((size_t)DEPTH * BATCH * 2048);
    float* adaz_attn = alloc((size_t)DEPTH * BATCH * 1024);
    float* film_ff   = alloc((size_t)DEPTH * BATCH * 2048);
    float* adaz_ff   = alloc((size_t)DEPTH * BATCH * 1024);
    float* gates     = alloc((size_t)NTOK * 16);
    float* x         = alloc((size_t)NTOK * DIMSZ);
    float* xc        = alloc((size_t)NTOK * DIMSZ);
    float* o_pre     = alloc((size_t)NTOK * DIMSZ);  // doubles as xtmp for skip GEMMs
    float* vr        = alloc((size_t)NTOK * DIMSZ);
    float* qkv       = alloc((size_t)NTOK * 3072);
    float* skip0     = alloc((size_t)NTOK * DIMSZ);
    float* skip1     = alloc((size_t)NTOK * DIMSZ);
    float* skip2     = alloc((size_t)NTOK * DIMSZ);
    float* h_ff      = alloc((size_t)NTOK * 2 * DFF);
    float* act       = alloc((size_t)NTOK * DFF);
    float* skips[3] = {skip0, skip1, skip2};
    (void)in_sizes; (void)n_in; (void)out_size; (void)ws_size;

    // conditioning (once)
    fourier_kernel<<<BATCH, 512, 0, stream>>>(times, fw, fourier);
    cond_kernel<<<16, 256, 0, stream>>>(fourier, tcond_w, tcond_b, cond);
    film_gemv<<<dim3(8, DEPTH), 256, 0, stream>>>(cond, afilm_w, afilm_b, film_attn, 2048, 0);
    film_gemv<<<dim3(4, DEPTH), 256, 0, stream>>>(cond, aadaz_w, aadaz_b, adaz_attn, 1024, 1);
    film_gemv<<<dim3(8, DEPTH), 256, 0, stream>>>(cond, ffilm_w, ffilm_b, film_ff, 2048, 0);
    film_gemv<<<dim3(4, DEPTH), 256, 0, stream>>>(cond, fadaz_w, fadaz_b, adaz_ff, 1024, 1);

    hipMemcpyAsync(x, in_x, sizeof(float) * (size_t)NTOK * DIMSZ,
                   hipMemcpyDeviceToDevice, stream);

    for (int i = 0; i < DEPTH; i++) {
        if (i < 3) {
            hipMemcpyAsync(skips[i], x, sizeof(float) * (size_t)NTOK * DIMSZ,
                           hipMemcpyDeviceToDevice, stream);
        } else {
            // x_new = [x, skip] @ skip_w[i-3]  ==  x@W_top + skip@W_bot
            const float* Wt = skip_w + (size_t)(i - 3) * 2048 * 1024;
            gemm_f32<<<dim3(8, 16), 256, 0, stream>>>(
                x, Wt, nullptr, nullptr, o_pre, NTOK, 1024, 1024, 0);
            gemm_f32<<<dim3(8, 16), 256, 0, stream>>>(
                skips[5 - i], Wt + (size_t)1024 * 1024, nullptr, nullptr, o_pre,
                NTOK, 1024, 1024, 1);
            hipMemcpyAsync(x, o_pre, sizeof(float) * (size_t)NTOK * DIMSZ,
                           hipMemcpyDeviceToDevice, stream);
        }

        ln_film_kernel<<<NTOK, 256, 0, stream>>>(x, film_attn + (size_t)i * BATCH * 2048, xc);
        gemm_f32<<<dim3(24, 16), 256, 0, stream>>>(
            xc, qkv_w + (size_t)i * 1024 * 3072, nullptr, nullptr, qkv,
            NTOK, 3072, 1024, 0);
        rope_kernel<<<(BATCH * SEQ * 2 * HEADS * 32) / 256, 256, 0, stream>>>(qkv, rfreqs);
        gates_kernel<<<NTOK, 256, 0, stream>>>(xc, gates_w + (size_t)i * 1024 * 16, gates);
        if (i == 0)
            copy_vr_kernel<<<(NTOK * 1024) / 256, 256, 0, stream>>>(qkv, vr);
        attn_kernel<<<BATCH * HEADS * SEQ, 256, 0, stream>>>(qkv, vr, gates, o_pre,
                                                             (i > 0) ? 1 : 0);
        gemm_f32<<<dim3(8, 16), 256, 0, stream>>>(
            o_pre, out_w + (size_t)i * 1024 * 1024, nullptr,
            adaz_attn + (size_t)i * BATCH * 1024, x, NTOK, 1024, 1024, 2);

        ln_film_kernel<<<NTOK, 256, 0, stream>>>(x, film_ff + (size_t)i * BATCH * 2048, xc);
        gemm_f32<<<dim3((2 * DFF + 127) / 128, 16), 256, 0, stream>>>(
            xc, ff_w1 + (size_t)i * 1024 * (2 * DFF), ff_b1 + (size_t)i * (2 * DFF),
            nullptr, h_ff, NTOK, 2 * DFF, 1024, 0);
        geglu_kernel<<<dim3((DFF + 255) / 256, NTOK), 256, 0, stream>>>(h_ff, act);
        gemm_f32<<<dim3(8, 16), 256, 0, stream>>>(
            act, ff_w2 + (size_t)i * DFF * 1024, ff_b2 + (size_t)i * 1024,
            adaz_ff + (size_t)i * BATCH * 1024, x, NTOK, 1024, DFF, 2);
    }

    final_kernel<<<NTOK, 256, 0, stream>>>(x, gamma, out);
}

// Round 2
// 6427.920 us; speedup vs baseline: 4.8868x; 4.8868x over previous
//
#include <hip/hip_runtime.h>
#include <math.h>
#include <stdint.h>

// Problem constants
#define DIMSZ 1024
#define DEPTH 6
#define HEADS 16
#define DHEAD 64
#define BATCH 2
#define SEQ   1024
#define DFF   2730            // int(1024*4*2/3)
#define DFF2  5460            // 2*DFF
#define DFF2P 5504            // padded to 43*128
#define DFFP  2752            // padded to 86*32
#define NTOK  (BATCH*SEQ)     // 2048

#define ASG __attribute__((address_space(1)))
#define ASL __attribute__((address_space(3)))

using short8 = __attribute__((ext_vector_type(8))) short;
using f32x4  = __attribute__((ext_vector_type(4))) float;

__device__ __forceinline__ short f2bf(float f) {
    unsigned u = __float_as_uint(f);
    unsigned r = (u + 0x7fffu + ((u >> 16) & 1u)) >> 16;
    return (short)r;
}
__device__ __forceinline__ float bf2f(short s) {
    return __uint_as_float(((unsigned)(unsigned short)s) << 16);
}

__device__ __forceinline__ void gld16(const short* g, short* l) {
    __builtin_amdgcn_global_load_lds(
        reinterpret_cast<const ASG void*>(reinterpret_cast<uintptr_t>(g)),
        reinterpret_cast<ASL void*>(reinterpret_cast<uintptr_t>(l)),
        16, 0, 0);
}

// ================= bf16 MFMA GEMM: C(MxN) = A(MxK) @ Wt(N,K)^T =================
// 128x128 tile, BK=32, 4 waves (2x2 of 64x64), 16x16x32 bf16 MFMA.
// LDS tiles [128 rows][32 bf16] with 16B-chunk XOR swizzle: phys chunk
// p = c ^ ((row>>1)&3)  -> frag ds_read_b128 is 2-way (free).
// modes: 0 = Cf store (+bias); 1 = Cb(bf16) store w/ bias + Nreal guard;
//        2 = Cf += (acc (+bias)) * adaz[b][n]
__global__ __launch_bounds__(256)
void gemm_bf16(const short* __restrict__ A, int lda,
               const short* __restrict__ Bw, int ldb,
               const float* __restrict__ bias, const float* __restrict__ adaz,
               float* __restrict__ Cf, short* __restrict__ Cb,
               int M, int N, int K, int Nreal, int mode)
{
    __shared__ __align__(16) short As[4096];   // 128*32
    __shared__ __align__(16) short Bs[4096];
    const int tid  = threadIdx.x;
    const int m0   = blockIdx.y * 128, n0 = blockIdx.x * 128;
    const int wave = tid >> 6, lane = tid & 63;
    const int wy   = wave >> 1, wx = wave & 1;

    // staging geometry: 512 chunks of 16B per tile; chunk o -> row o>>2, phys c o&3
    const int o1 = tid, o2 = 256 + tid;
    const int r1 = o1 >> 2, lc1 = (o1 & 3) ^ ((r1 >> 1) & 3);
    const int r2 = o2 >> 2, lc2 = (o2 & 3) ^ ((r2 >> 1) & 3);
    const short* a1 = A  + (size_t)(m0 + r1) * lda + lc1 * 8;
    const short* a2 = A  + (size_t)(m0 + r2) * lda + lc2 * 8;
    const short* b1 = Bw + (size_t)(n0 + r1) * ldb + lc1 * 8;
    const short* b2 = Bw + (size_t)(n0 + r2) * ldb + lc2 * 8;
    short* dA1 = As + wave * 512;         // chunk (wave*64 + lane) slots
    short* dA2 = As + 2048 + wave * 512;
    short* dB1 = Bs + wave * 512;
    short* dB2 = Bs + 2048 + wave * 512;

    f32x4 acc[4][4];
    #pragma unroll
    for (int i = 0; i < 4; i++)
        #pragma unroll
        for (int j = 0; j < 4; j++) acc[i][j] = (f32x4){0.f, 0.f, 0.f, 0.f};

    // fragment LDS offsets (shorts)
    const int kq = lane >> 4, cl = lane & 15;
    int fa[4], fb[4];
    #pragma unroll
    for (int t = 0; t < 4; t++) {
        int mr = wy * 64 + t * 16 + cl;
        fa[t] = mr * 32 + (kq ^ ((mr >> 1) & 3)) * 8;
        int nr = wx * 64 + t * 16 + cl;
        fb[t] = nr * 32 + (kq ^ ((nr >> 1) & 3)) * 8;
    }

    for (int k0 = 0; k0 < K; k0 += 32) {
        __syncthreads();
        gld16(a1 + k0, dA1);
        gld16(a2 + k0, dA2);
        gld16(b1 + k0, dB1);
        gld16(b2 + k0, dB2);
        __syncthreads();
        short8 af[4], bf[4];
        #pragma unroll
        for (int t = 0; t < 4; t++) af[t] = *(const short8*)(As + fa[t]);
        #pragma unroll
        for (int t = 0; t < 4; t++) bf[t] = *(const short8*)(Bs + fb[t]);
        #pragma unroll
        for (int mt = 0; mt < 4; mt++)
            #pragma unroll
            for (int nt = 0; nt < 4; nt++)
                acc[mt][nt] = __builtin_amdgcn_mfma_f32_16x16x32_bf16(
                    af[mt], bf[nt], acc[mt][nt], 0, 0, 0);
    }

    const int rq = (lane >> 4) * 4;
    #pragma unroll
    for (int mt = 0; mt < 4; mt++) {
        #pragma unroll
        for (int nt = 0; nt < 4; nt++) {
            int gn = n0 + wx * 64 + nt * 16 + cl;
            f32x4 a = acc[mt][nt];
            #pragma unroll
            for (int r = 0; r < 4; r++) {
                int gm = m0 + wy * 64 + mt * 16 + rq + r;
                float v = a[r];
                if (mode == 0) {
                    if (bias) v += bias[gn];
                    Cf[(size_t)gm * N + gn] = v;
                } else if (mode == 1) {
                    float o = (gn < Nreal) ? (v + bias[gn]) : 0.f;
                    Cb[(size_t)gm * N + gn] = f2bf(o);
                } else {
                    if (bias) v += bias[gn];
                    int bb = gm >> 10;
                    Cf[(size_t)gm * N + gn] += v * adaz[(size_t)bb * N + gn];
                }
            }
        }
    }
}

// ============ weight transpose+cast: W(K,N) f32 -> Wt(Np,Kp) bf16, zero-pad ============
__global__ __launch_bounds__(256)
void transpose_cast(const float* __restrict__ W, short* __restrict__ Wt,
                    int K, int N, int Kp, int Np)
{
    __shared__ float tile[32][33];
    int n0 = blockIdx.x * 32, k0 = blockIdx.y * 32;
    int tx = threadIdx.x, ty = threadIdx.y;   // 32 x 8
    #pragma unroll
    for (int r = 0; r < 4; r++) {
        int k = k0 + ty + r * 8, n = n0 + tx;
        float v = (k < K && n < N) ? W[(size_t)k * N + n] : 0.f;
        tile[ty + r * 8][tx] = v;
    }
    __syncthreads();
    #pragma unroll
    for (int r = 0; r < 4; r++) {
        int n = n0 + ty + r * 8, k = k0 + tx;
        Wt[(size_t)n * Kp + k] = f2bf(tile[tx][ty + r * 8]);
    }
}

// ---------------- conditioning ----------------
__global__ void fourier_kernel(const float* __restrict__ times,
                               const float* __restrict__ fw,
                               float* __restrict__ fourier) {
    int b = blockIdx.x;
    int j = threadIdx.x;  // 512
    float t = times[b];
    float f = t * fw[j] * 6.2831853071795864f;
    fourier[b * 1025 + 1 + j]   = sinf(f);
    fourier[b * 1025 + 513 + j] = cosf(f);
    if (j == 0) fourier[b * 1025] = t;
}

__global__ __launch_bounds__(256)
void cond_kernel(const float* __restrict__ fourier, const float* __restrict__ Wt,
                 const float* __restrict__ bt, float* __restrict__ cond) {
    int col = blockIdx.x * 256 + threadIdx.x;
    float a0 = 0.f, a1 = 0.f;
    for (int r = 0; r < 1025; r++) {
        float w = Wt[(size_t)r * 4096 + col];
        a0 = fmaf(fourier[r], w, a0);
        a1 = fmaf(fourier[1025 + r], w, a1);
    }
    float bb = bt[col];
    a0 += bb; a1 += bb;
    cond[col]        = a0 / (1.f + __expf(-a0));
    cond[4096 + col] = a1 / (1.f + __expf(-a1));
}

__global__ __launch_bounds__(256)
void film_gemv(const float* __restrict__ cond, const float* __restrict__ W,
               const float* __restrict__ bias, float* __restrict__ out,
               int Mcols, int sig) {
    int l = blockIdx.y;
    int col = blockIdx.x * 256 + threadIdx.x;
    const float* Wl = W + (size_t)l * 4096 * Mcols;
    float a0 = 0.f, a1 = 0.f;
    for (int r = 0; r < 4096; r++) {
        float w = Wl[(size_t)r * Mcols + col];
        a0 = fmaf(cond[r], w, a0);
        a1 = fmaf(cond[4096 + r], w, a1);
    }
    float bb = bias[(size_t)l * Mcols + col];
    a0 += bb; a1 += bb;
    if (sig) { a0 = 1.f / (1.f + __expf(-a0)); a1 = 1.f / (1.f + __expf(-a1)); }
    out[((size_t)l * BATCH + 0) * Mcols + col] = a0;
    out[((size_t)l * BATCH + 1) * Mcols + col] = a1;
}

// ---------------- LayerNorm + film -> bf16 ----------------
__device__ __forceinline__ float block_reduce_sum256(float v, float* red) {
    int tid = threadIdx.x;
    red[tid] = v; __syncthreads();
    #pragma unroll
    for (int s = 128; s > 0; s >>= 1) {
        if (tid < s) red[tid] += red[tid + s];
        __syncthreads();
    }
    float r = red[0]; __syncthreads();
    return r;
}

__global__ __launch_bounds__(256)
void ln_film_kernel(const float* __restrict__ x, const float* __restrict__ film,
                    short* __restrict__ xc) {
    __shared__ float red[256];
    int row = blockIdx.x;
    int b = row >> 10;
    int tid = threadIdx.x;
    float v[4];
    float s = 0.f, sq = 0.f;
    #pragma unroll
    for (int k = 0; k < 4; k++) {
        v[k] = x[(size_t)row * DIMSZ + tid + k * 256];
        s += v[k]; sq += v[k] * v[k];
    }
    s  = block_reduce_sum256(s, red);
    sq = block_reduce_sum256(sq, red);
    float mu = s * (1.f / 1024.f);
    float var = sq * (1.f / 1024.f) - mu * mu;
    float rstd = rsqrtf(var + 1e-5f);
    #pragma unroll
    for (int k = 0; k < 4; k++) {
        int c = tid + k * 256;
        float g  = film[(size_t)b * 2048 + c];
        float bb = film[(size_t)b * 2048 + 1024 + c];
        xc[(size_t)row * DIMSZ + c] = f2bf((v[k] - mu) * rstd * (g + 1.f) + bb);
    }
}

// ---------------- gates ----------------
__global__ __launch_bounds__(256)
void gates_kernel(const short* __restrict__ xc, const float* __restrict__ W,
                  float* __restrict__ gates) {
    __shared__ float red[256];
    int row = blockIdx.x;
    int tid = threadIdx.x;
    int col = tid & 15, part = tid >> 4;
    float acc = 0.f;
    int r0 = part * 64;
    for (int r = 0; r < 64; r++)
        acc = fmaf(bf2f(xc[(size_t)row * DIMSZ + r0 + r]), W[(r0 + r) * 16 + col], acc);
    red[tid] = acc; __syncthreads();
    #pragma unroll
    for (int s = 8; s > 0; s >>= 1) {
        if (part < s) red[part * 16 + col] += red[(part + s) * 16 + col];
        __syncthreads();
    }
    if (tid < 16) gates[(size_t)row * 16 + tid] = 1.f / (1.f + __expf(-red[tid]));
}

// ---------------- RoPE in-place on q,k of qkv (fp32) ----------------
__global__ __launch_bounds__(256)
void rope_kernel(float* __restrict__ qkv, const float* __restrict__ freqs) {
    int idx = blockIdx.x * 256 + threadIdx.x;
    int p = idx & 31;
    int h = (idx >> 5) & 15;
    int t = (idx >> 9) & 1;
    int bn = idx >> 10;
    int n = bn & 1023;
    size_t base = ((size_t)bn * 3 + t) * 1024 + h * 64 + 2 * p;
    float f = freqs[n * 64 + 2 * p];
    float c = cosf(f), sn = sinf(f);
    float x0 = qkv[base], x1 = qkv[base + 1];
    qkv[base]     = x0 * c - x1 * sn;
    qkv[base + 1] = x1 * c + x0 * sn;
}

__global__ __launch_bounds__(256)
void copy_vr_kernel(const float* __restrict__ qkv, float* __restrict__ vr) {
    int idx = blockIdx.x * 256 + threadIdx.x;
    int bn = idx >> 10, c = idx & 1023;
    vr[idx] = qkv[((size_t)bn * 3 + 2) * 1024 + c];
}

// ---------------- flash-style tiled attention ----------------
// grid (16, B*H); block 256. Q-tile 64 rows (held in regs, pre-scaled),
// K/V tiles 64 staged in LDS, online softmax, softcap, causal, v-mix, gate.
// Output bf16 (NTOK, 1024).
__global__ __launch_bounds__(256)
void attn_tile_kernel(const float* __restrict__ qkv, const float* __restrict__ vr,
                      const float* __restrict__ gates, short* __restrict__ o,
                      int mix)
{
    __shared__ float Ks[64][68];
    __shared__ float Vs[64][68];
    __shared__ float Ssm[64][65];
    __shared__ float red_max[64][4];
    __shared__ float red_sum[64][4];

    int qt = 15 - blockIdx.x;         // heavy tiles first
    int bh = blockIdx.y;
    int b = bh >> 4, h = bh & 15;
    int tid = threadIdx.x;
    int q = tid >> 2, c4 = tid & 3;   // c4: score j-group in phase1, d-quarter in phase2

    // Q row -> registers, pre-scaled by DHEAD^-0.5
    const float4* qg = (const float4*)(qkv +
        ((size_t)(b * 1024 + qt * 64 + q) * 3 + 0) * 1024 + h * 64);
    float4 qreg[16];
    #pragma unroll
    for (int c = 0; c < 16; c++) {
        float4 t = qg[c];
        qreg[c] = make_float4(t.x * 0.125f, t.y * 0.125f, t.z * 0.125f, t.w * 0.125f);
    }
    float4 o4[4];
    #pragma unroll
    for (int c = 0; c < 4; c++) o4[c] = make_float4(0.f, 0.f, 0.f, 0.f);
    float m = -3.0e38f, l = 0.f;

    for (int kt = 0; kt <= qt; kt++) {
        __syncthreads();   // protect Ks/Vs/Ssm/red from previous iter readers
        {
            size_t jrow = (size_t)(b * 1024 + kt * 64 + q);
            const float4* kg = (const float4*)(qkv + (jrow * 3 + 1) * 1024 + h * 64);
            const float4* vg = (const float4*)(qkv + (jrow * 3 + 2) * 1024 + h * 64);
            float4* kd = (float4*)&Ks[q][0];
            float4* vd = (float4*)&Vs[q][0];
            if (mix) {
                const float4* vrg = (const float4*)(vr + jrow * 1024 + h * 64);
                #pragma unroll
                for (int c = 0; c < 4; c++) {
                    int idx = c4 * 4 + c;
                    kd[idx] = kg[idx];
                    float4 v = vg[idx], w = vrg[idx];
                    vd[idx] = make_float4(0.5f * (v.x + w.x), 0.5f * (v.y + w.y),
                                          0.5f * (v.z + w.z), 0.5f * (v.w + w.w));
                }
            } else {
                #pragma unroll
                for (int c = 0; c < 4; c++) {
                    int idx = c4 * 4 + c;
                    kd[idx] = kg[idx];
                    vd[idx] = vg[idx];
                }
            }
        }
        __syncthreads();   // staging complete

        // phase 1: 16 scores per thread, j = c4 + 4*jj (conflict-free Ks reads)
        float sreg[16];
        float tmax = -3.0e38f;
        #pragma unroll
        for (int jj = 0; jj < 16; jj++) {
            int j = c4 + 4 * jj;
            const float4* kr = (const float4*)&Ks[j][0];
            float s = 0.f;
            #pragma unroll
            for (int c = 0; c < 16; c++) {
                float4 kk = kr[c]; float4 qq = qreg[c];
                s = fmaf(qq.x, kk.x, s); s = fmaf(qq.y, kk.y, s);
                s = fmaf(qq.z, kk.z, s); s = fmaf(qq.w, kk.w, s);
            }
            float xa = s * 0.02f;                       // s/SOFTCAP
            xa = fminf(fmaxf(xa, -15.f), 15.f);
            float e = __expf(2.f * xa);
            s = 50.f * (e - 1.f) / (e + 1.f);           // softcap tanh
            if (kt == qt && j > q) s = -3.0e38f;        // causal
            sreg[jj] = s;
            tmax = fmaxf(tmax, s);
        }
        red_max[q][c4] = tmax;
        __syncthreads();
        float mt = fmaxf(fmaxf(red_max[q][0], red_max[q][1]),
                         fmaxf(red_max[q][2], red_max[q][3]));
        float m_new = fmaxf(m, mt);
        float alpha = __expf(m - m_new);
        m = m_new;
        float psum = 0.f;
        #pragma unroll
        for (int jj = 0; jj < 16; jj++) {
            float p = __expf(sreg[jj] - m_new);
            Ssm[q][c4 + 4 * jj] = p;
            psum += p;
        }
        red_sum[q][c4] = psum;
        #pragma unroll
        for (int c = 0; c < 4; c++) {
            o4[c].x *= alpha; o4[c].y *= alpha; o4[c].z *= alpha; o4[c].w *= alpha;
        }
        __syncthreads();   // Ssm + red_sum ready
        l = l * alpha + (red_sum[q][0] + red_sum[q][1] + red_sum[q][2] + red_sum[q][3]);

        // phase 2: O += P @ V ; thread owns (q, d-quarter c4)
        for (int j = 0; j < 64; j++) {
            float p = Ssm[q][j];
            const float4* vv = (const float4*)&Vs[j][0];
            #pragma unroll
            for (int c = 0; c < 4; c++) {
                float4 v = vv[c4 * 4 + c];
                o4[c].x = fmaf(p, v.x, o4[c].x);
                o4[c].y = fmaf(p, v.y, o4[c].y);
                o4[c].z = fmaf(p, v.z, o4[c].z);
                o4[c].w = fmaf(p, v.w, o4[c].w);
            }
        }
    }

    float g = gates[(size_t)(b * 1024 + qt * 64 + q) * 16 + h];
    float sc = g / l;
    size_t obase = (size_t)(b * 1024 + qt * 64 + q) * 1024 + h * 64 + c4 * 16;
    #pragma unroll
    for (int c = 0; c < 4; c++) {
        o[obase + c * 4 + 0] = f2bf(o4[c].x * sc);
        o[obase + c * 4 + 1] = f2bf(o4[c].y * sc);
        o[obase + c * 4 + 2] = f2bf(o4[c].z * sc);
        o[obase + c * 4 + 3] = f2bf(o4[c].w * sc);
    }
}

// ---------------- GEGLU (bf16 in/out, padded strides, zero pads) ----------------
__global__ __launch_bounds__(256)
void geglu_kernel(const short* __restrict__ h, short* __restrict__ act) {
    int c = blockIdx.x * 256 + threadIdx.x;
    int row = blockIdx.y;
    if (c >= DFFP) return;
    float r = 0.f;
    if (c < DFF) {
        float a = bf2f(h[(size_t)row * DFF2P + c]);
        float g = bf2f(h[(size_t)row * DFF2P + DFF + c]);
        float gl = 0.5f * g * (1.f + erff(g * 0.70710678118654752f));
        r = gl * a;
    }
    act[(size_t)row * DFFP + c] = f2bf(r);
}

// ---------------- strided cast fp32 -> bf16 (for skip concat halves) ----------------
__global__ __launch_bounds__(256)
void cast_strided_kernel(const float* __restrict__ src, short* __restrict__ dst,
                         int dstride, int coff) {
    int idx = blockIdx.x * 256 + threadIdx.x;
    int row = idx >> 10, col = idx & 1023;
    dst[(size_t)row * dstride + coff + col] = f2bf(src[idx]);
}

// ---------------- final: unit-norm * 32 * (gamma+1) ----------------
__global__ __launch_bounds__(256)
void final_kernel(const float* __restrict__ x, const float* __restrict__ gamma,
                  float* __restrict__ out) {
    __shared__ float red[256];
    int row = blockIdx.x;
    int tid = threadIdx.x;
    float v[4]; float sq = 0.f;
    #pragma unroll
    for (int k = 0; k < 4; k++) {
        v[k] = x[(size_t)row * DIMSZ + tid + k * 256];
        sq += v[k] * v[k];
    }
    sq = block_reduce_sum256(sq, red);
    float norm = sqrtf(sq);
    float rs = 32.f / fmaxf(norm, 1e-12f);
    #pragma unroll
    for (int k = 0; k < 4; k++) {
        int c = tid + k * 256;
        out[(size_t)row * DIMSZ + c] = v[k] * rs * (gamma[c] + 1.f);
    }
}

extern "C" void kernel_launch(void* const* d_in, const int* in_sizes, int n_in,
                              void* d_out, int out_size, void* d_ws, size_t ws_size,
                              hipStream_t stream) {
    const float* in_x    = (const float*)d_in[0];
    const float* times   = (const float*)d_in[1];
    const float* rfreqs  = (const float*)d_in[2];
    const float* fw      = (const float*)d_in[3];
    const float* tcond_w = (const float*)d_in[4];
    const float* tcond_b = (const float*)d_in[5];
    const float* skip_w  = (const float*)d_in[6];
    const float* afilm_w = (const float*)d_in[7];
    const float* afilm_b = (const float*)d_in[8];
    const float* aadaz_w = (const float*)d_in[9];
    const float* aadaz_b = (const float*)d_in[10];
    const float* qkv_w   = (const float*)d_in[11];
    const float* gates_w = (const float*)d_in[12];
    const float* out_w   = (const float*)d_in[13];
    const float* ffilm_w = (const float*)d_in[14];
    const float* ffilm_b = (const float*)d_in[15];
    const float* fadaz_w = (const float*)d_in[16];
    const float* fadaz_b = (const float*)d_in[17];
    const float* ff_w1   = (const float*)d_in[18];
    const float* ff_b1   = (const float*)d_in[19];
    const float* ff_w2   = (const float*)d_in[20];
    const float* ff_b2   = (const float*)d_in[21];
    const float* gamma   = (const float*)d_in[22];
    float* out = (float*)d_out;
    (void)in_sizes; (void)n_in; (void)out_size; (void)ws_size;

    // ---- workspace layout (~138 MB) ----
    float* wsf = (float*)d_ws;
    size_t off = 0;
    auto allocf = [&](size_t n) { float* p = wsf + off; off += n; return p; };
    float* fourier   = allocf(BATCH * 1025);
    float* cond      = allocf(BATCH * 4096);
    float* film_attn = allocf((size_t)DEPTH * BATCH * 2048);
    float* adaz_attn = allocf((size_t)DEPTH * BATCH * 1024);
    float* film_ff   = allocf((size_t)DEPTH * BATCH * 2048);
    float* adaz_ff   = allocf((size_t)DEPTH * BATCH * 1024);
    float* gates     = allocf((size_t)NTOK * 16);
    float* x         = allocf((size_t)NTOK * DIMSZ);
    float* vr        = allocf((size_t)NTOK * DIMSZ);
    float* qkv       = allocf((size_t)NTOK * 3072);

    short* wss = (short*)(wsf + off);
    size_t soff = 0;
    auto allocs = [&](size_t n) { short* p = wss + soff; soff += n; return p; };
    short* xc_bf   = allocs((size_t)NTOK * DIMSZ);
    short* o_bf    = allocs((size_t)NTOK * DIMSZ);
    short* h_bf    = allocs((size_t)NTOK * DFF2P);
    short* act_bf  = allocs((size_t)NTOK * DFFP);
    short* xskip0  = allocs((size_t)NTOK * 2048);
    short* xskip1  = allocs((size_t)NTOK * 2048);
    short* xskip2  = allocs((size_t)NTOK * 2048);
    short* Wt_qkv  = allocs((size_t)3072 * 1024);
    short* Wt_out  = allocs((size_t)1024 * 1024);
    short* Wt_ff1  = allocs((size_t)DFF2P * 1024);
    short* Wt_ff2  = allocs((size_t)1024 * DFFP);
    short* Wt_skip = allocs((size_t)1024 * 2048);
    short* xskips[3] = {xskip0, xskip1, xskip2};

    // ---- conditioning (once) ----
    fourier_kernel<<<BATCH, 512, 0, stream>>>(times, fw, fourier);
    cond_kernel<<<16, 256, 0, stream>>>(fourier, tcond_w, tcond_b, cond);
    film_gemv<<<dim3(8, DEPTH), 256, 0, stream>>>(cond, afilm_w, afilm_b, film_attn, 2048, 0);
    film_gemv<<<dim3(4, DEPTH), 256, 0, stream>>>(cond, aadaz_w, aadaz_b, adaz_attn, 1024, 1);
    film_gemv<<<dim3(8, DEPTH), 256, 0, stream>>>(cond, ffilm_w, ffilm_b, film_ff, 2048, 0);
    film_gemv<<<dim3(4, DEPTH), 256, 0, stream>>>(cond, fadaz_w, fadaz_b, adaz_ff, 1024, 1);

    hipMemcpyAsync(x, in_x, sizeof(float) * (size_t)NTOK * DIMSZ,
                   hipMemcpyDeviceToDevice, stream);

    dim3 tb(32, 8);
    for (int i = 0; i < DEPTH; i++) {
        // per-layer weight transposes (reused buffers)
        transpose_cast<<<dim3(96, 32), tb, 0, stream>>>(
            qkv_w + (size_t)i * 1024 * 3072, Wt_qkv, 1024, 3072, 1024, 3072);
        transpose_cast<<<dim3(32, 32), tb, 0, stream>>>(
            out_w + (size_t)i * 1024 * 1024, Wt_out, 1024, 1024, 1024, 1024);
        transpose_cast<<<dim3(172, 32), tb, 0, stream>>>(
            ff_w1 + (size_t)i * 1024 * DFF2, Wt_ff1, 1024, DFF2, 1024, DFF2P);
        transpose_cast<<<dim3(32, 86), tb, 0, stream>>>(
            ff_w2 + (size_t)i * DFF * 1024, Wt_ff2, DFF, 1024, DFFP, 1024);

        if (i < 3) {
            // save skip: bf16 cast of x into right half of xskip[i]
            cast_strided_kernel<<<8192, 256, 0, stream>>>(x, xskips[i], 2048, 1024);
        } else {
            transpose_cast<<<dim3(32, 64), tb, 0, stream>>>(
                skip_w + (size_t)(i - 3) * 2048 * 1024, Wt_skip, 2048, 1024, 2048, 1024);
            // current x into left half, then x = [x, skip] @ skip_w
            cast_strided_kernel<<<8192, 256, 0, stream>>>(x, xskips[5 - i], 2048, 0);
            gemm_bf16<<<dim3(8, 16), 256, 0, stream>>>(
                xskips[5 - i], 2048, Wt_skip, 2048, nullptr, nullptr,
                x, nullptr, NTOK, 1024, 2048, 1024, 0);
        }

        // attention block
        ln_film_kernel<<<NTOK, 256, 0, stream>>>(x, film_attn + (size_t)i * BATCH * 2048, xc_bf);
        gemm_bf16<<<dim3(24, 16), 256, 0, stream>>>(
            xc_bf, 1024, Wt_qkv, 1024, nullptr, nullptr,
            qkv, nullptr, NTOK, 3072, 1024, 3072, 0);
        rope_kernel<<<(NTOK * 2 * HEADS * 32) / 256, 256, 0, stream>>>(qkv, rfreqs);
        gates_kernel<<<NTOK, 256, 0, stream>>>(xc_bf, gates_w + (size_t)i * 1024 * 16, gates);
        if (i == 0)
            copy_vr_kernel<<<(NTOK * 1024) / 256, 256, 0, stream>>>(qkv, vr);
        attn_tile_kernel<<<dim3(16, BATCH * HEADS), 256, 0, stream>>>(
            qkv, vr, gates, o_bf, (i > 0) ? 1 : 0);
        gemm_bf16<<<dim3(8, 16), 256, 0, stream>>>(
            o_bf, 1024, Wt_out, 1024, nullptr, adaz_attn + (size_t)i * BATCH * 1024,
            x, nullptr, NTOK, 1024, 1024, 1024, 2);

        // FF block
        ln_film_kernel<<<NTOK, 256, 0, stream>>>(x, film_ff + (size_t)i * BATCH * 2048, xc_bf);
        gemm_bf16<<<dim3(43, 16), 256, 0, stream>>>(
            xc_bf, 1024, Wt_ff1, 1024, ff_b1 + (size_t)i * DFF2, nullptr,
            nullptr, h_bf, NTOK, DFF2P, 1024, DFF2, 1);
        geglu_kernel<<<dim3(11, NTOK), 256, 0, stream>>>(h_bf, act_bf);
        gemm_bf16<<<dim3(8, 16), 256, 0, stream>>>(
            act_bf, DFFP, Wt_ff2, DFFP, ff_b2 + (size_t)i * 1024,
            adaz_ff + (size_t)i * BATCH * 1024,
            x, nullptr, NTOK, 1024, DFFP, 1024, 2);
    }

    final_kernel<<<NTOK, 256, 0, stream>>>(x, gamma, out);
}